// Round 8
// baseline (364.319 us; speedup 1.0000x reference)
//
#include <hip/hip_runtime.h>
#include <hip/hip_bf16.h>

#define NSLOPE 0.2f

typedef short bf16x8 __attribute__((ext_vector_type(8)));
typedef float f32x4 __attribute__((ext_vector_type(4)));

__device__ __forceinline__ unsigned short f2b(float f) {
    unsigned u = __float_as_uint(f);
    unsigned r = (u + 0x7FFFu + ((u >> 16) & 1u)) >> 16;
    return (unsigned short)r;
}
__device__ __forceinline__ float b2f_lo(unsigned w) {
    return __uint_as_float(w << 16);
}
__device__ __forceinline__ float b2f_hi(unsigned w) {
    return __uint_as_float(w & 0xFFFF0000u);
}
__device__ __forceinline__ float b2f_s(short s) {
    return __uint_as_float(((unsigned)(unsigned short)s) << 16);
}

// ---------------- CSR build -------------------------------------------------

__global__ __launch_bounds__(256) void hist_deg(const int* __restrict__ ei,
                                                int* __restrict__ deg, int E,
                                                int n) {
    int t = blockIdx.x * 256 + threadIdx.x;
    int Etot = E + n;
    if (t >= Etot) return;
    int d = (t < E) ? ei[E + t] : (t - E);
    atomicAdd(&deg[d], 1);
}

__global__ __launch_bounds__(256) void scan_blk(const int* __restrict__ deg,
                                                int* __restrict__ local,
                                                int* __restrict__ bsum, int n) {
    __shared__ int sm[256];
    const int base = blockIdx.x * 1024;
    const int t = threadIdx.x;
    const int i0 = base + t * 4;
    int v0 = 0, v1 = 0, v2 = 0, v3 = 0;
    if (i0 + 3 < n) {
        int4 v = *(const int4*)(deg + i0);
        v0 = v.x; v1 = v.y; v2 = v.z; v3 = v.w;
    } else {
        if (i0 < n) v0 = deg[i0];
        if (i0 + 1 < n) v1 = deg[i0 + 1];
        if (i0 + 2 < n) v2 = deg[i0 + 2];
    }
    int s = v0 + v1 + v2 + v3;
    sm[t] = s;
    __syncthreads();
    for (int off = 1; off < 256; off <<= 1) {
        int val = (t >= off) ? sm[t - off] : 0;
        __syncthreads();
        sm[t] += val;
        __syncthreads();
    }
    int ex = sm[t] - s;
    if (t == 255) bsum[blockIdx.x] = sm[255];
    if (i0 < n) local[i0] = ex;
    if (i0 + 1 < n) local[i0 + 1] = ex + v0;
    if (i0 + 2 < n) local[i0 + 2] = ex + v0 + v1;
    if (i0 + 3 < n) local[i0 + 3] = ex + v0 + v1 + v2;
}

__global__ __launch_bounds__(256) void scan_top(const int* __restrict__ bsum,
                                                int* __restrict__ boff,
                                                int nb) {
    __shared__ int sm[256];
    const int t = threadIdx.x;
    int s = (t < nb) ? bsum[t] : 0;
    sm[t] = s;
    __syncthreads();
    for (int off = 1; off < 256; off <<= 1) {
        int val = (t >= off) ? sm[t - off] : 0;
        __syncthreads();
        sm[t] += val;
        __syncthreads();
    }
    if (t < nb) boff[t] = sm[t] - s;
}

__global__ __launch_bounds__(256) void scan_add(const int* __restrict__ local,
                                                const int* __restrict__ boff,
                                                int* __restrict__ rowstart,
                                                int* __restrict__ cursor,
                                                int n, int Etot) {
    int i = blockIdx.x * 256 + threadIdx.x;
    if (i > n) return;
    if (i == n) {
        rowstart[n] = Etot;
        return;
    }
    int v = local[i] + boff[i >> 10];
    rowstart[i] = v;
    cursor[i] = v;
}

// writes (src,dst) pairs in dst-sorted CSR order
__global__ __launch_bounds__(256) void fill_csr(const int* __restrict__ ei,
                                                int* __restrict__ cursor,
                                                int2* __restrict__ csr2, int E,
                                                int n) {
    int t = blockIdx.x * 256 + threadIdx.x;
    int Etot = E + n;
    if (t >= Etot) return;
    int s, d;
    if (t < E) { s = ei[t]; d = ei[E + t]; } else { s = d = t - E; }
    int pos = atomicAdd(&cursor[d], 1);
    csr2[pos] = make_int2(s, d);
}

// ---------------- weight prep: fp32 [K][NC] -> bf16 [NC][K] (transposed) ----
__global__ __launch_bounds__(256) void prep_weights(
    const float* __restrict__ W0, const float* __restrict__ W1,
    const float* __restrict__ W2, const float* __restrict__ W3,
    const float* __restrict__ resW, const float* __restrict__ linW0,
    const float* __restrict__ linW1, const float* __restrict__ linB0,
    short* __restrict__ Wt0, short* __restrict__ Wt1, short* __restrict__ Wt2,
    short* __restrict__ Wt3, short* __restrict__ WtR, short* __restrict__ WtU,
    short* __restrict__ WtV, short* __restrict__ WbT,
    float* __restrict__ bias128) {
    const float* src;
    short* dst;
    int K, NC, rowoff = 0;
    switch (blockIdx.x) {
        case 0: src = W0; dst = Wt0; K = 128; NC = 256; break;
        case 1: src = W1; dst = Wt1; K = 64; NC = 256; break;
        case 2: src = W2; dst = Wt2; K = 64; NC = 256; break;
        case 3: src = W3; dst = Wt3; K = 64; NC = 256; break;
        case 4: src = resW; dst = WtR; K = 128; NC = 64; break;
        case 5: src = linW0; dst = WtU; K = 64; NC = 64; break;
        case 6: src = linW0; dst = WtV; K = 64; NC = 64; rowoff = 64; break;
        case 7: src = linW1; dst = WbT; K = 64; NC = 64; break;
        default: {  // bias pad: [b0 | 0]
            if (blockIdx.y == 0 && threadIdx.x < 128)
                bias128[threadIdx.x] =
                    (threadIdx.x < 64) ? linB0[threadIdx.x] : 0.f;
            return;
        }
    }
    for (int idx = blockIdx.y * 256 + threadIdx.x; idx < K * NC;
         idx += 256 * 16) {
        int k = idx / NC, nn = idx - k * NC;
        dst[nn * K + k] = (short)f2b(src[(k + rowoff) * NC + nn]);
    }
}

__global__ __launch_bounds__(256) void convert_x(const float* __restrict__ x,
                                                 short* __restrict__ xb,
                                                 int total) {
    int idx = (blockIdx.x * 256 + threadIdx.x) * 4;
    if (idx >= total) return;
    float4 v = *(const float4*)(x + idx);
    ushort4 o;
    o.x = f2b(v.x); o.y = f2b(v.y); o.z = f2b(v.z); o.w = f2b(v.w);
    *(ushort4*)(xb + idx) = o;
}

// ---------------- MFMA node GEMM -------------------------------------------
// OM=0: OutF fp32 (+bias); OM=1: Hq pack + fused attn scores; OM=2: OutB bf16
template <int K, int NG, int OM>
__global__ __launch_bounds__(256) void mfma_gemm(
    const short* __restrict__ Xb, const short* __restrict__ Wt,
    const float* __restrict__ bias, uint2* __restrict__ Hq,
    const float* __restrict__ as_l, const float* __restrict__ ad_l,
    float* __restrict__ Ssrc, float* __restrict__ Sdst,
    float* __restrict__ OutF, short* __restrict__ OutB, int n) {
    constexpr int XSTR = K + 8;
    constexpr int NC = NG * 16;
    __shared__ __align__(16) short Xs[64 * XSTR];
    __shared__ __align__(16) short Ws[NC * 40];
    const int tid = threadIdx.x;
    const int nb = blockIdx.x * 64;
    constexpr int CH = K / 8;
    for (int idx = tid; idx < 64 * CH; idx += 256) {
        int row = idx / CH, c = idx - row * CH;
        uint4 v = make_uint4(0, 0, 0, 0);
        if (nb + row < n)
            v = *(const uint4*)(Xb + (size_t)(nb + row) * K + c * 8);
        *(uint4*)(Xs + row * XSTR + c * 8) = v;
    }
    const int wid = tid >> 6;
    const int lane = tid & 63;
    const int t = lane & 15, quad = lane >> 4;
    f32x4 acc[NG];
#pragma unroll
    for (int g = 0; g < NG; ++g) acc[g] = (f32x4){0.f, 0.f, 0.f, 0.f};
#pragma unroll 1
    for (int kc = 0; kc < K / 32; ++kc) {
        __syncthreads();
        for (int idx = tid; idx < NC * 4; idx += 256) {
            int row = idx >> 2, c = idx & 3;
            uint4 v = *(const uint4*)(Wt + (size_t)row * K + kc * 32 + c * 8);
            *(uint4*)(Ws + row * 40 + c * 8) = v;
        }
        __syncthreads();
        bf16x8 a =
            *(const bf16x8*)(Xs + (wid * 16 + t) * XSTR + kc * 32 + quad * 8);
#pragma unroll
        for (int g = 0; g < NG; ++g) {
            bf16x8 b = *(const bf16x8*)(Ws + (g * 16 + t) * 40 + quad * 8);
            acc[g] = __builtin_amdgcn_mfma_f32_16x16x32_bf16(a, b, acc[g], 0, 0, 0);
        }
    }
    if (OM == 1) {
#pragma unroll
        for (int r = 0; r < 4; ++r) {
            int node = nb + wid * 16 + quad * 4 + r;
            if (node >= n) continue;
#pragma unroll
            for (int g = 0; g < 4; ++g) {
                unsigned p01 = ((unsigned)f2b(acc[g + 4][r]) << 16) |
                               (unsigned)f2b(acc[g][r]);
                unsigned p23 = ((unsigned)f2b(acc[g + 12][r]) << 16) |
                               (unsigned)f2b(acc[g + 8][r]);
                Hq[(size_t)node * 64 + g * 16 + t] = make_uint2(p01, p23);
            }
        }
        float asv[16], adv[16];
#pragma unroll
        for (int G = 0; G < 16; ++G) {
            asv[G] = as_l[G * 16 + t];
            adv[G] = ad_l[G * 16 + t];
        }
#pragma unroll
        for (int r = 0; r < 4; ++r) {
            int node = nb + wid * 16 + quad * 4 + r;
            float pv[8];
#pragma unroll
            for (int h = 0; h < 4; ++h) {
                float ps = 0.f, pd = 0.f;
#pragma unroll
                for (int j = 0; j < 4; ++j) {
                    float a = acc[h * 4 + j][r];
                    ps += a * asv[h * 4 + j];
                    pd += a * adv[h * 4 + j];
                }
                pv[h] = ps;
                pv[4 + h] = pd;
            }
#pragma unroll
            for (int off = 1; off < 16; off <<= 1) {
#pragma unroll
                for (int i = 0; i < 8; ++i) pv[i] += __shfl_xor(pv[i], off, 64);
            }
            if (t == 0 && node < n) {
                *(float4*)&Ssrc[node * 4] =
                    make_float4(pv[0], pv[1], pv[2], pv[3]);
                *(float4*)&Sdst[node * 4] =
                    make_float4(pv[4], pv[5], pv[6], pv[7]);
            }
        }
    } else {
        float bv[NG];
#pragma unroll
        for (int g = 0; g < NG; ++g) bv[g] = bias ? bias[g * 16 + t] : 0.f;
#pragma unroll
        for (int r = 0; r < 4; ++r) {
            int node = nb + wid * 16 + quad * 4 + r;
            if (node >= n) continue;
            if (OM == 0) {
#pragma unroll
                for (int g = 0; g < NG; ++g)
                    OutF[(size_t)node * NC + g * 16 + t] = acc[g][r] + bv[g];
            } else {
#pragma unroll
                for (int g = 0; g < NG; ++g)
                    OutB[(size_t)node * NC + g * 16 + t] =
                        (short)f2b(acc[g][r] + bv[g]);
            }
        }
    }
}

// ---------------- per-edge softmax numerators (CSR order) -------------------
__global__ __launch_bounds__(256) void edge_scores(
    const int2* __restrict__ csr2, const float* __restrict__ Ssrc,
    const float* __restrict__ Sdst, float4* __restrict__ p4, int Etot) {
    int e = blockIdx.x * 256 + threadIdx.x;
    if (e >= Etot) return;
    int2 sd = csr2[e];
    float4 ss = *(const float4*)&Ssrc[sd.x * 4];
    float4 dd = *(const float4*)&Sdst[sd.y * 4];
    float c0 = ss.x + dd.x, c1 = ss.y + dd.y, c2 = ss.z + dd.z,
          c3 = ss.w + dd.w;
    c0 = c0 > 0.f ? c0 : NSLOPE * c0;
    c1 = c1 > 0.f ? c1 : NSLOPE * c1;
    c2 = c2 > 0.f ? c2 : NSLOPE * c2;
    c3 = c3 > 0.f ? c3 : NSLOPE * c3;
    p4[e] = make_float4(__expf(c0), __expf(c1), __expf(c2), __expf(c3));
}

// ---------------- fused GAT aggregate + epilogue (gather, 2 edges/wave) -----
// Lanes 0-31 process edge e, lanes 32-63 edge e+1. Each lane loads uint4
// (channels 2cl, 2cl+1 x 4 heads). Halves combine via shfl_xor(32).
__global__ __launch_bounds__(256) void gat_gather(
    const int2* __restrict__ csr2, const int* __restrict__ rowstart,
    const float4* __restrict__ p4, const uint4* __restrict__ Hq4,
    const float* __restrict__ gb, const float* __restrict__ resid,
    float* __restrict__ featOut, unsigned* __restrict__ featB2, int n) {
    const int wid = threadIdx.x >> 6;
    const int lane = threadIdx.x & 63;
    const int half = lane >> 5;
    const int cl = lane & 31;
    const int node = blockIdx.x * 4 + wid;
    if (node >= n) return;
    const int start = rowstart[node];
    const int end = rowstart[node + 1];
    float uA0 = 0.f, uA1 = 0.f, uA2 = 0.f, uA3 = 0.f;
    float uB0 = 0.f, uB1 = 0.f, uB2 = 0.f, uB3 = 0.f;
    float z0 = 0.f, z1 = 0.f, z2 = 0.f, z3 = 0.f;
#pragma unroll 2
    for (int e = start + half; e < end; e += 2) {
        int sj = csr2[e].x;
        float4 p = p4[e];
        uint4 hv = Hq4[(size_t)sj * 32 + cl];
        uA0 += p.x * b2f_lo(hv.x);
        uA1 += p.y * b2f_hi(hv.x);
        uA2 += p.z * b2f_lo(hv.y);
        uA3 += p.w * b2f_hi(hv.y);
        uB0 += p.x * b2f_lo(hv.z);
        uB1 += p.y * b2f_hi(hv.z);
        uB2 += p.z * b2f_lo(hv.w);
        uB3 += p.w * b2f_hi(hv.w);
        z0 += p.x; z1 += p.y; z2 += p.z; z3 += p.w;
    }
    // combine the two halves
    uA0 += __shfl_xor(uA0, 32, 64);
    uA1 += __shfl_xor(uA1, 32, 64);
    uA2 += __shfl_xor(uA2, 32, 64);
    uA3 += __shfl_xor(uA3, 32, 64);
    uB0 += __shfl_xor(uB0, 32, 64);
    uB1 += __shfl_xor(uB1, 32, 64);
    uB2 += __shfl_xor(uB2, 32, 64);
    uB3 += __shfl_xor(uB3, 32, 64);
    z0 += __shfl_xor(z0, 32, 64);
    z1 += __shfl_xor(z1, 32, 64);
    z2 += __shfl_xor(z2, 32, 64);
    z3 += __shfl_xor(z3, 32, 64);
    if (half == 0) {
        float2 gbv = *(const float2*)&gb[2 * cl];
        float2 rv = *(const float2*)&resid[(size_t)node * 64 + 2 * cl];
        float valA =
            0.25f * (uA0 / z0 + uA1 / z1 + uA2 / z2 + uA3 / z3) + gbv.x + rv.x;
        float valB =
            0.25f * (uB0 / z0 + uB1 / z1 + uB2 / z2 + uB3 / z3) + gbv.y + rv.y;
        valA = valA > 0.f ? valA : expm1f(valA);
        valB = valB > 0.f ? valB : expm1f(valB);
        *(float2*)&featOut[(size_t)node * 64 + 2 * cl] =
            make_float2(valA, valB);
        featB2[(size_t)node * 32 + cl] =
            ((unsigned)f2b(valB) << 16) | (unsigned)f2b(valA);
    }
}

// ---------------- edge classifier (MFMA, 128-edge tile) ---------------------
// UV: [node][128] bf16 (U cols 0..63 incl b0, V cols 64..127)
__global__ __launch_bounds__(256) void edge_mlp3(
    const int* __restrict__ ei, const unsigned* __restrict__ UV,
    const short* __restrict__ WbT, const float* __restrict__ bb,
    const float* __restrict__ Wc, const float* __restrict__ bc,
    float* __restrict__ out, int E) {
    __shared__ __align__(16) short t1b[128 * 72];
    __shared__ __align__(16) short wbs[64 * 72];
    const int tid = threadIdx.x;
    const int eBase = blockIdx.x * 128;
    for (int idx = tid; idx < 512; idx += 256) {
        int row = idx >> 3, c = idx & 7;
        *(uint4*)(wbs + row * 72 + c * 8) =
            *(const uint4*)(WbT + row * 64 + c * 8);
    }
    {
        const int j = tid & 31;
        const int eg = tid >> 5;
        int rr[16], cc[16];
#pragma unroll
        for (int it = 0; it < 16; ++it) {
            int e = eBase + it * 8 + eg;
            rr[it] = (e < E) ? ei[e] : 0;
            cc[it] = (e < E) ? ei[E + e] : 0;
        }
#pragma unroll
        for (int it = 0; it < 16; ++it) {
            unsigned uu = UV[(size_t)rr[it] * 64 + j];
            unsigned vv = UV[(size_t)cc[it] * 64 + 32 + j];
            float lo = fmaxf(b2f_lo(uu) + b2f_lo(vv), 0.f);
            float hi = fmaxf(b2f_hi(uu) + b2f_hi(vv), 0.f);
            *(unsigned*)(t1b + (it * 8 + eg) * 72 + j * 2) =
                ((unsigned)f2b(hi) << 16) | (unsigned)f2b(lo);
        }
    }
    __syncthreads();
    const int w = tid >> 6, lane = tid & 63;
    const int t = lane & 15, quad = lane >> 4;
    float wcv[4], bbv[4];
#pragma unroll
    for (int g = 0; g < 4; ++g) {
        wcv[g] = Wc[g * 16 + t];
        bbv[g] = bb[g * 16 + t];
    }
    const float bcv = bc[0];
#pragma unroll
    for (int mt = 0; mt < 2; ++mt) {
        const int rbase = w * 32 + mt * 16;
        f32x4 acc[4];
#pragma unroll
        for (int g = 0; g < 4; ++g) acc[g] = (f32x4){0.f, 0.f, 0.f, 0.f};
#pragma unroll
        for (int kc = 0; kc < 2; ++kc) {
            bf16x8 a =
                *(const bf16x8*)(t1b + (rbase + t) * 72 + kc * 32 + quad * 8);
#pragma unroll
            for (int g = 0; g < 4; ++g) {
                bf16x8 b =
                    *(const bf16x8*)(wbs + (g * 16 + t) * 72 + kc * 32 + quad * 8);
                acc[g] =
                    __builtin_amdgcn_mfma_f32_16x16x32_bf16(a, b, acc[g], 0, 0, 0);
            }
        }
#pragma unroll
        for (int r = 0; r < 4; ++r) {
            int el = rbase + quad * 4 + r;
            float part = 0.f;
#pragma unroll
            for (int g = 0; g < 4; ++g) {
                float t1v = b2f_s(t1b[el * 72 + g * 16 + t]);
                float t2 = fmaxf(acc[g][r] + bbv[g] + t1v, 0.f);
                part += t2 * wcv[g];
            }
            part += __shfl_xor(part, 1, 64);
            part += __shfl_xor(part, 2, 64);
            part += __shfl_xor(part, 4, 64);
            part += __shfl_xor(part, 8, 64);
            int e = eBase + el;
            if (t == 0 && e < E) out[e] = part + bcv;
        }
    }
}

extern "C" void kernel_launch(void* const* d_in, const int* in_sizes, int n_in,
                              void* d_out, int out_size, void* d_ws,
                              size_t ws_size, hipStream_t stream) {
    const float* x = (const float*)d_in[0];
    const int* ei = (const int*)d_in[1];
    const float* W0 = (const float*)d_in[2];
    const float* W1 = (const float*)d_in[3];
    const float* W2 = (const float*)d_in[4];
    const float* W3 = (const float*)d_in[5];
    const float* a_src = (const float*)d_in[6];
    const float* a_dst = (const float*)d_in[7];
    const float* gat_b = (const float*)d_in[8];
    const float* res_W = (const float*)d_in[9];
    const float* res_b = (const float*)d_in[10];
    const float* lin_W0 = (const float*)d_in[11];
    const float* lin_b0 = (const float*)d_in[12];
    const float* lin_W1 = (const float*)d_in[13];
    const float* lin_b1 = (const float*)d_in[14];
    const float* lin_W2 = (const float*)d_in[15];
    const float* lin_b2 = (const float*)d_in[16];
    float* out = (float*)d_out;

    const int N = in_sizes[0] / 128;  // 20000
    const int E = in_sizes[1] / 2;    // 320000
    const int Etot = E + N;

    float* ws = (float*)d_ws;
    uint2* Hq = (uint2*)ws;                            // N*64 uint2
    float* feat = (float*)(Hq + (size_t)N * 64);       // N*64 f32
    float* res = feat + (size_t)N * 64;                // N*64 f32
    short* xb = (short*)(res + (size_t)N * 64);        // N*128 bf16
    short* featb = xb;                                 // alias (N*64 bf16)
    float* Ssrc = (float*)(xb + (size_t)N * 128);      // N*4
    float* Sdst = Ssrc + (size_t)N * 4;                // N*4
    short* Wt0 = (short*)(Sdst + (size_t)N * 4);       // 256*128
    short* Wt1 = Wt0 + 256 * 128;                      // 256*64
    short* Wt2 = Wt1 + 256 * 64;
    short* Wt3 = Wt2 + 256 * 64;
    short* WtR = Wt3 + 256 * 64;                       // 64*128
    short* WtU = WtR + 64 * 128;                       // 64*64 (U cols)
    short* WtV = WtU + 64 * 64;                        // 64*64 (V cols, contig)
    short* WbT = WtV + 64 * 64;                        // 64*64
    int* deg = (int*)(WbT + 64 * 64);                  // N
    int* rowstart = deg + N;                           // N+1
    int* cursor = rowstart + N + 1;                    // N
    int* locals = cursor + N;                          // N
    int* bsum = locals + N;                            // 256
    int* boff = bsum + 256;                            // 256
    float* bias128 = (float*)(boff + 256);             // 128
    int2* csr2 = (int2*)(((size_t)(bias128 + 128) + 15) & ~(size_t)15);  // Etot
    float4* p4 = (float4*)(((size_t)(csr2 + Etot) + 15) & ~(size_t)15);  // Etot
    short* UVb = (short*)Hq;                           // alias, N*128 bf16

    const int gemmBlocks = (N + 63) / 64;
    const int edgeBlocks = (Etot + 255) / 256;
    const int nodeW = (N + 3) / 4;
    const int scanBlocks = (N + 1023) / 1024;
    const short* Wts[4] = {Wt0, Wt1, Wt2, Wt3};

    // CSR build (parallel scan)
    hipMemsetAsync(deg, 0, (size_t)N * sizeof(int), stream);
    hist_deg<<<edgeBlocks, 256, 0, stream>>>(ei, deg, E, N);
    scan_blk<<<scanBlocks, 256, 0, stream>>>(deg, locals, bsum, N);
    scan_top<<<1, 256, 0, stream>>>(bsum, boff, scanBlocks);
    scan_add<<<(N + 256) / 256, 256, 0, stream>>>(locals, boff, rowstart,
                                                  cursor, N, Etot);
    fill_csr<<<edgeBlocks, 256, 0, stream>>>(ei, cursor, csr2, E, N);

    // weight prep + x conversion
    prep_weights<<<dim3(9, 16), 256, 0, stream>>>(
        W0, W1, W2, W3, res_W, lin_W0, lin_W1, lin_b0, Wt0, Wt1, Wt2, Wt3,
        WtR, WtU, WtV, WbT, bias128);
    convert_x<<<(N * 128 / 4 + 255) / 256, 256, 0, stream>>>(x, xb, N * 128);

    for (int i = 0; i < 4; ++i) {
        if (i == 0)
            mfma_gemm<128, 16, 1><<<gemmBlocks, 256, 0, stream>>>(
                xb, Wt0, nullptr, Hq, a_src, a_dst, Ssrc, Sdst, nullptr,
                nullptr, N);
        else
            mfma_gemm<64, 16, 1><<<gemmBlocks, 256, 0, stream>>>(
                featb, Wts[i], nullptr, Hq, a_src + i * 256, a_dst + i * 256,
                Ssrc, Sdst, nullptr, nullptr, N);
        edge_scores<<<edgeBlocks, 256, 0, stream>>>(csr2, Ssrc, Sdst, p4,
                                                    Etot);
        if (i == 0)  // residual projection (reads xb; precedes gather's featb write)
            mfma_gemm<128, 4, 0><<<gemmBlocks, 256, 0, stream>>>(
                xb, WtR, res_b, nullptr, nullptr, nullptr, nullptr, nullptr,
                res, nullptr, N);
        const float* resid = (i == 0) ? res : feat;
        gat_gather<<<nodeW, 256, 0, stream>>>(
            csr2, rowstart, p4, (const uint4*)Hq, gat_b + i * 64, resid, feat,
            (unsigned*)featb, N);
    }

    // edge classifier heads, single GEMM: UV = feat@[W0_top|W0_bot] + [b0|0]
    mfma_gemm<64, 8, 2><<<gemmBlocks, 256, 0, stream>>>(
        featb, WtU, bias128, nullptr, nullptr, nullptr, nullptr, nullptr,
        nullptr, UVb, N);
    edge_mlp3<<<(E + 127) / 128, 256, 0, stream>>>(
        ei, (const unsigned*)UVb, WbT, lin_b1, lin_W2, lin_b2, out, E);
}

// Round 9
// 353.670 us; speedup vs baseline: 1.0301x; 1.0301x over previous
//
#include <hip/hip_runtime.h>
#include <hip/hip_bf16.h>

#define NSLOPE 0.2f

typedef short bf16x8 __attribute__((ext_vector_type(8)));
typedef float f32x4 __attribute__((ext_vector_type(4)));

__device__ __forceinline__ unsigned short f2b(float f) {
    unsigned u = __float_as_uint(f);
    unsigned r = (u + 0x7FFFu + ((u >> 16) & 1u)) >> 16;
    return (unsigned short)r;
}
__device__ __forceinline__ float b2f_lo(unsigned w) {
    return __uint_as_float(w << 16);
}
__device__ __forceinline__ float b2f_hi(unsigned w) {
    return __uint_as_float(w & 0xFFFF0000u);
}
__device__ __forceinline__ float b2f_s(short s) {
    return __uint_as_float(((unsigned)(unsigned short)s) << 16);
}
__device__ __forceinline__ unsigned packb(float lo, float hi) {
    return ((unsigned)f2b(hi) << 16) | (unsigned)f2b(lo);
}

// ---------------- CSR build -------------------------------------------------

__global__ __launch_bounds__(256) void hist_deg(const int* __restrict__ ei,
                                                int* __restrict__ deg, int E,
                                                int n) {
    int t = blockIdx.x * 256 + threadIdx.x;
    int Etot = E + n;
    if (t >= Etot) return;
    int d = (t < E) ? ei[E + t] : (t - E);
    atomicAdd(&deg[d], 1);
}

__global__ __launch_bounds__(256) void scan_blk(const int* __restrict__ deg,
                                                int* __restrict__ local,
                                                int* __restrict__ bsum, int n) {
    __shared__ int sm[256];
    const int base = blockIdx.x * 1024;
    const int t = threadIdx.x;
    const int i0 = base + t * 4;
    int v0 = 0, v1 = 0, v2 = 0, v3 = 0;
    if (i0 + 3 < n) {
        int4 v = *(const int4*)(deg + i0);
        v0 = v.x; v1 = v.y; v2 = v.z; v3 = v.w;
    } else {
        if (i0 < n) v0 = deg[i0];
        if (i0 + 1 < n) v1 = deg[i0 + 1];
        if (i0 + 2 < n) v2 = deg[i0 + 2];
    }
    int s = v0 + v1 + v2 + v3;
    sm[t] = s;
    __syncthreads();
    for (int off = 1; off < 256; off <<= 1) {
        int val = (t >= off) ? sm[t - off] : 0;
        __syncthreads();
        sm[t] += val;
        __syncthreads();
    }
    int ex = sm[t] - s;
    if (t == 255) bsum[blockIdx.x] = sm[255];
    if (i0 < n) local[i0] = ex;
    if (i0 + 1 < n) local[i0 + 1] = ex + v0;
    if (i0 + 2 < n) local[i0 + 2] = ex + v0 + v1;
    if (i0 + 3 < n) local[i0 + 3] = ex + v0 + v1 + v2;
}

__global__ __launch_bounds__(256) void scan_top(const int* __restrict__ bsum,
                                                int* __restrict__ boff,
                                                int nb) {
    __shared__ int sm[256];
    const int t = threadIdx.x;
    int s = (t < nb) ? bsum[t] : 0;
    sm[t] = s;
    __syncthreads();
    for (int off = 1; off < 256; off <<= 1) {
        int val = (t >= off) ? sm[t - off] : 0;
        __syncthreads();
        sm[t] += val;
        __syncthreads();
    }
    if (t < nb) boff[t] = sm[t] - s;
}

__global__ __launch_bounds__(256) void scan_add(const int* __restrict__ local,
                                                const int* __restrict__ boff,
                                                int* __restrict__ rowstart,
                                                int* __restrict__ cursor,
                                                int n, int Etot) {
    int i = blockIdx.x * 256 + threadIdx.x;
    if (i > n) return;
    if (i == n) {
        rowstart[n] = Etot;
        return;
    }
    int v = local[i] + boff[i >> 10];
    rowstart[i] = v;
    cursor[i] = v;
}

__global__ __launch_bounds__(256) void fill_csr(const int* __restrict__ ei,
                                                int* __restrict__ cursor,
                                                int2* __restrict__ csr2, int E,
                                                int n) {
    int t = blockIdx.x * 256 + threadIdx.x;
    int Etot = E + n;
    if (t >= Etot) return;
    int s, d;
    if (t < E) { s = ei[t]; d = ei[E + t]; } else { s = d = t - E; }
    int pos = atomicAdd(&cursor[d], 1);
    csr2[pos] = make_int2(s, d);
}

// ---------------- weight prep -----------------------------------------------
// cases 0-3: WtC_l[j][4*K] = head-concat transpose: WtC[j*4K + h*K + k] =
//            W_l[k*256 + h*64 + j]   (K=128 for l=0 else 64)
// case 4: WtR[nn*128+k] = resW[k*64+nn];  5/6: WtU/WtV from linW0; 7: WbT
// case 8: bias128 = [lin_b0 | 0]
__global__ __launch_bounds__(256) void prep_weights(
    const float* __restrict__ W0, const float* __restrict__ W1,
    const float* __restrict__ W2, const float* __restrict__ W3,
    const float* __restrict__ resW, const float* __restrict__ linW0,
    const float* __restrict__ linW1, const float* __restrict__ linB0,
    short* __restrict__ WtC0, short* __restrict__ WtC1,
    short* __restrict__ WtC2, short* __restrict__ WtC3,
    short* __restrict__ WtR, short* __restrict__ WtU, short* __restrict__ WtV,
    short* __restrict__ WbT, float* __restrict__ bias128) {
    const int bx = blockIdx.x;
    if (bx < 4) {
        const float* src = (bx == 0) ? W0 : (bx == 1) ? W1 : (bx == 2) ? W2 : W3;
        short* dst = (bx == 0) ? WtC0 : (bx == 1) ? WtC1 : (bx == 2) ? WtC2 : WtC3;
        const int K = (bx == 0) ? 128 : 64;
        const int total = 64 * 4 * K;
        for (int idx = blockIdx.y * 256 + threadIdx.x; idx < total;
             idx += 256 * 16) {
            int j = idx / (4 * K);
            int rem = idx - j * 4 * K;
            int h = rem / K, k = rem - h * K;
            dst[idx] = (short)f2b(src[k * 256 + h * 64 + j]);
        }
        return;
    }
    const float* src;
    short* dst;
    int K, NC, rowoff = 0;
    switch (bx) {
        case 4: src = resW; dst = WtR; K = 128; NC = 64; break;
        case 5: src = linW0; dst = WtU; K = 64; NC = 64; break;
        case 6: src = linW0; dst = WtV; K = 64; NC = 64; rowoff = 64; break;
        case 7: src = linW1; dst = WbT; K = 64; NC = 64; break;
        default: {
            if (blockIdx.y == 0 && threadIdx.x < 128)
                bias128[threadIdx.x] =
                    (threadIdx.x < 64) ? linB0[threadIdx.x] : 0.f;
            return;
        }
    }
    for (int idx = blockIdx.y * 256 + threadIdx.x; idx < K * NC;
         idx += 256 * 16) {
        int k = idx / NC, nn = idx - k * NC;
        dst[nn * K + k] = (short)f2b(src[(k + rowoff) * NC + nn]);
    }
}

// wsd_l[k][j] = sum_c W_l[k, h*64+c] * a[h,c];  j<4: a_src head j; j>=4: a_dst
// block l=0..3; l==0 -> wsd0 (K=128), else wsdL + (l-1)*64*8 (K=64)
__global__ __launch_bounds__(256) void prep_wsd(
    const float* __restrict__ W0, const float* __restrict__ W1,
    const float* __restrict__ W2, const float* __restrict__ W3,
    const float* __restrict__ a_src, const float* __restrict__ a_dst,
    float* __restrict__ wsd0, float* __restrict__ wsdL) {
    const int l = blockIdx.x;
    const float* W = (l == 0) ? W0 : (l == 1) ? W1 : (l == 2) ? W2 : W3;
    const int K = (l == 0) ? 128 : 64;
    float* dst = (l == 0) ? wsd0 : wsdL + (l - 1) * 64 * 8;
    for (int idx = threadIdx.x; idx < K * 8; idx += 256) {
        int k = idx >> 3, j = idx & 7, h = j & 3;
        const float* av = ((j < 4) ? a_src : a_dst) + l * 256 + h * 64;
        const float* wr = W + k * 256 + h * 64;
        float s = 0.f;
#pragma unroll 8
        for (int c = 0; c < 64; ++c) s += wr[c] * av[c];
        dst[k * 8 + j] = s;
    }
}

// ---------------- convert x -> bf16 + layer-0 attention scores --------------
__global__ __launch_bounds__(256) void convert_x_scores(
    const float* __restrict__ x, const float* __restrict__ wsd0,
    unsigned* __restrict__ xb2, float* __restrict__ Ssrc,
    float* __restrict__ Sdst, int n) {
    const int wid = threadIdx.x >> 6;
    const int lane = threadIdx.x & 63;
    const int node = blockIdx.x * 4 + wid;
    if (node >= n) return;
    float2 xv = *(const float2*)&x[(size_t)node * 128 + lane * 2];
    xb2[(size_t)node * 64 + lane] = packb(xv.x, xv.y);
    float pv[8];
    const float* w0 = &wsd0[(lane * 2) * 8];
    const float* w1 = &wsd0[(lane * 2 + 1) * 8];
#pragma unroll
    for (int j = 0; j < 8; ++j) pv[j] = xv.x * w0[j] + xv.y * w1[j];
#pragma unroll
    for (int off = 1; off < 64; off <<= 1) {
#pragma unroll
        for (int j = 0; j < 8; ++j) pv[j] += __shfl_xor(pv[j], off, 64);
    }
    if (lane == 0) {
        *(float4*)&Ssrc[node * 4] = make_float4(pv[0], pv[1], pv[2], pv[3]);
        *(float4*)&Sdst[node * 4] = make_float4(pv[4], pv[5], pv[6], pv[7]);
    }
}

// ---------------- MFMA node GEMM (res / UV heads) ---------------------------
// OM=0: OutF fp32 (+bias); OM=2: OutB bf16 (+bias)
template <int K, int NG, int OM>
__global__ __launch_bounds__(256) void mfma_gemm(
    const short* __restrict__ Xb, const short* __restrict__ Wt,
    const float* __restrict__ bias, float* __restrict__ OutF,
    short* __restrict__ OutB, int n) {
    constexpr int XSTR = K + 8;
    constexpr int NC = NG * 16;
    __shared__ __align__(16) short Xs[64 * XSTR];
    __shared__ __align__(16) short Ws[NC * 40];
    const int tid = threadIdx.x;
    const int nb = blockIdx.x * 64;
    constexpr int CH = K / 8;
    for (int idx = tid; idx < 64 * CH; idx += 256) {
        int row = idx / CH, c = idx - row * CH;
        uint4 v = make_uint4(0, 0, 0, 0);
        if (nb + row < n)
            v = *(const uint4*)(Xb + (size_t)(nb + row) * K + c * 8);
        *(uint4*)(Xs + row * XSTR + c * 8) = v;
    }
    const int wid = tid >> 6;
    const int lane = tid & 63;
    const int t = lane & 15, quad = lane >> 4;
    f32x4 acc[NG];
#pragma unroll
    for (int g = 0; g < NG; ++g) acc[g] = (f32x4){0.f, 0.f, 0.f, 0.f};
#pragma unroll 1
    for (int kc = 0; kc < K / 32; ++kc) {
        __syncthreads();
        for (int idx = tid; idx < NC * 4; idx += 256) {
            int row = idx >> 2, c = idx & 3;
            uint4 v = *(const uint4*)(Wt + (size_t)row * K + kc * 32 + c * 8);
            *(uint4*)(Ws + row * 40 + c * 8) = v;
        }
        __syncthreads();
        bf16x8 a =
            *(const bf16x8*)(Xs + (wid * 16 + t) * XSTR + kc * 32 + quad * 8);
#pragma unroll
        for (int g = 0; g < NG; ++g) {
            bf16x8 b = *(const bf16x8*)(Ws + (g * 16 + t) * 40 + quad * 8);
            acc[g] = __builtin_amdgcn_mfma_f32_16x16x32_bf16(a, b, acc[g], 0, 0, 0);
        }
    }
    float bv[NG];
#pragma unroll
    for (int g = 0; g < NG; ++g) bv[g] = bias ? bias[g * 16 + t] : 0.f;
#pragma unroll
    for (int r = 0; r < 4; ++r) {
        int node = nb + wid * 16 + quad * 4 + r;
        if (node >= n) continue;
        if (OM == 0) {
#pragma unroll
            for (int g = 0; g < NG; ++g)
                OutF[(size_t)node * NC + g * 16 + t] = acc[g][r] + bv[g];
        } else {
#pragma unroll
            for (int g = 0; g < NG; ++g)
                OutB[(size_t)node * NC + g * 16 + t] =
                    (short)f2b(acc[g][r] + bv[g]);
        }
    }
}

// ---------------- layer GEMM: out = aggB @ WtC + b + resid, ELU, + scores ---
// KK = 512 (layer0) or 256. Epilogue writes feat fp32, featb bf16, and
// (SCORES) next-layer Ssrc/Sdst via wsd[64][8].
template <int KK, bool SCORES>
__global__ __launch_bounds__(256) void gemm_layer(
    const short* __restrict__ Xb, const short* __restrict__ Wt,
    const float* __restrict__ gbias, const float* __restrict__ resid,
    const float* __restrict__ wsd, float* __restrict__ feat,
    short* __restrict__ featb, float* __restrict__ Ssrc,
    float* __restrict__ Sdst, int n) {
    __shared__ __align__(16) short Xs[64 * 136];
    __shared__ __align__(16) short Ws[64 * 40];
    const int tid = threadIdx.x;
    const int nb = blockIdx.x * 64;
    const int wid = tid >> 6;
    const int lane = tid & 63;
    const int t = lane & 15, quad = lane >> 4;
    f32x4 acc[4];
#pragma unroll
    for (int g = 0; g < 4; ++g) acc[g] = (f32x4){0.f, 0.f, 0.f, 0.f};
#pragma unroll 1
    for (int c0 = 0; c0 < KK / 128; ++c0) {
        __syncthreads();
        for (int idx = tid; idx < 1024; idx += 256) {
            int row = idx >> 4, c = idx & 15;
            uint4 v = make_uint4(0, 0, 0, 0);
            if (nb + row < n)
                v = *(const uint4*)(Xb + (size_t)(nb + row) * KK + c0 * 128 +
                                    c * 8);
            *(uint4*)(Xs + row * 136 + c * 8) = v;
        }
#pragma unroll 1
        for (int kc = 0; kc < 4; ++kc) {
            __syncthreads();
            for (int idx = tid; idx < 256; idx += 256) {
                int row = idx >> 2, c = idx & 3;
                uint4 v = *(const uint4*)(Wt + (size_t)row * KK + c0 * 128 +
                                          kc * 32 + c * 8);
                *(uint4*)(Ws + row * 40 + c * 8) = v;
            }
            __syncthreads();
            bf16x8 a =
                *(const bf16x8*)(Xs + (wid * 16 + t) * 136 + kc * 32 + quad * 8);
#pragma unroll
            for (int g = 0; g < 4; ++g) {
                bf16x8 b = *(const bf16x8*)(Ws + (g * 16 + t) * 40 + quad * 8);
                acc[g] =
                    __builtin_amdgcn_mfma_f32_16x16x32_bf16(a, b, acc[g], 0, 0, 0);
            }
        }
    }
    float bv[4];
#pragma unroll
    for (int g = 0; g < 4; ++g) bv[g] = gbias[g * 16 + t];
    float wsv[4][8];
    if (SCORES) {
#pragma unroll
        for (int g = 0; g < 4; ++g) {
            float4 lo = *(const float4*)&wsd[(g * 16 + t) * 8];
            float4 hi = *(const float4*)&wsd[(g * 16 + t) * 8 + 4];
            wsv[g][0] = lo.x; wsv[g][1] = lo.y; wsv[g][2] = lo.z;
            wsv[g][3] = lo.w; wsv[g][4] = hi.x; wsv[g][5] = hi.y;
            wsv[g][6] = hi.z; wsv[g][7] = hi.w;
        }
    }
#pragma unroll
    for (int r = 0; r < 4; ++r) {
        int node = nb + wid * 16 + quad * 4 + r;
        bool ok = node < n;
        float val[4];
#pragma unroll
        for (int g = 0; g < 4; ++g) {
            float v = acc[g][r] + bv[g];
            if (ok) v += resid[(size_t)node * 64 + g * 16 + t];
            v = v > 0.f ? v : expm1f(v);
            val[g] = v;
            if (ok) {
                feat[(size_t)node * 64 + g * 16 + t] = v;
                featb[(size_t)node * 64 + g * 16 + t] = (short)f2b(v);
            }
        }
        if (SCORES) {
            float pv[8];
#pragma unroll
            for (int j = 0; j < 8; ++j) {
                pv[j] = val[0] * wsv[0][j] + val[1] * wsv[1][j] +
                        val[2] * wsv[2][j] + val[3] * wsv[3][j];
            }
#pragma unroll
            for (int off = 1; off < 16; off <<= 1) {
#pragma unroll
                for (int j = 0; j < 8; ++j) pv[j] += __shfl_xor(pv[j], off, 64);
            }
            if (t == 0 && ok) {
                *(float4*)&Ssrc[node * 4] =
                    make_float4(pv[0], pv[1], pv[2], pv[3]);
                *(float4*)&Sdst[node * 4] =
                    make_float4(pv[4], pv[5], pv[6], pv[7]);
            }
        }
    }
}

// ---------------- per-edge softmax numerators (CSR order) -------------------
__global__ __launch_bounds__(256) void edge_scores(
    const int2* __restrict__ csr2, const float* __restrict__ Ssrc,
    const float* __restrict__ Sdst, float4* __restrict__ p4, int Etot) {
    int e = blockIdx.x * 256 + threadIdx.x;
    if (e >= Etot) return;
    int2 sd = csr2[e];
    float4 ss = *(const float4*)&Ssrc[sd.x * 4];
    float4 dd = *(const float4*)&Sdst[sd.y * 4];
    float c0 = ss.x + dd.x, c1 = ss.y + dd.y, c2 = ss.z + dd.z,
          c3 = ss.w + dd.w;
    c0 = c0 > 0.f ? c0 : NSLOPE * c0;
    c1 = c1 > 0.f ? c1 : NSLOPE * c1;
    c2 = c2 > 0.f ? c2 : NSLOPE * c2;
    c3 = c3 > 0.f ? c3 : NSLOPE * c3;
    p4[e] = make_float4(__expf(c0), __expf(c1), __expf(c2), __expf(c3));
}

// ---------------- gather in INPUT space: agg_h[d] = 0.25/z_h * sum p_eh x[s] -
// K=128 (layer0): one edge/wave, lane covers ch 2l,2l+1; aggB[d][h*64+l] u32
__global__ __launch_bounds__(256) void gat_gather128(
    const int2* __restrict__ csr2, const int* __restrict__ rowstart,
    const float4* __restrict__ p4, const unsigned* __restrict__ xin,
    unsigned* __restrict__ aggB, int n) {
    const int wid = threadIdx.x >> 6;
    const int lane = threadIdx.x & 63;
    const int node = blockIdx.x * 4 + wid;
    if (node >= n) return;
    const int start = rowstart[node];
    const int end = rowstart[node + 1];
    float u00 = 0.f, u01 = 0.f, u10 = 0.f, u11 = 0.f;
    float u20 = 0.f, u21 = 0.f, u30 = 0.f, u31 = 0.f;
    float z0 = 0.f, z1 = 0.f, z2 = 0.f, z3 = 0.f;
#pragma unroll 4
    for (int e = start; e < end; ++e) {
        int sj = csr2[e].x;
        float4 p = p4[e];
        unsigned fv = xin[(size_t)sj * 64 + lane];
        float f0 = b2f_lo(fv), f1 = b2f_hi(fv);
        u00 += p.x * f0; u01 += p.x * f1;
        u10 += p.y * f0; u11 += p.y * f1;
        u20 += p.z * f0; u21 += p.z * f1;
        u30 += p.w * f0; u31 += p.w * f1;
        z0 += p.x; z1 += p.y; z2 += p.z; z3 += p.w;
    }
    float i0 = 0.25f / z0, i1 = 0.25f / z1, i2 = 0.25f / z2, i3 = 0.25f / z3;
    size_t base = (size_t)node * 256;
    aggB[base + lane] = packb(u00 * i0, u01 * i0);
    aggB[base + 64 + lane] = packb(u10 * i1, u11 * i1);
    aggB[base + 128 + lane] = packb(u20 * i2, u21 * i2);
    aggB[base + 192 + lane] = packb(u30 * i3, u31 * i3);
}

// K=64 (layers 1-3): two edges/wave (half=lane>>5), lane covers ch 2cl,2cl+1
__global__ __launch_bounds__(256) void gat_gather64(
    const int2* __restrict__ csr2, const int* __restrict__ rowstart,
    const float4* __restrict__ p4, const unsigned* __restrict__ fin,
    unsigned* __restrict__ aggB, int n) {
    const int wid = threadIdx.x >> 6;
    const int lane = threadIdx.x & 63;
    const int half = lane >> 5;
    const int cl = lane & 31;
    const int node = blockIdx.x * 4 + wid;
    if (node >= n) return;
    const int start = rowstart[node];
    const int end = rowstart[node + 1];
    float u00 = 0.f, u01 = 0.f, u10 = 0.f, u11 = 0.f;
    float u20 = 0.f, u21 = 0.f, u30 = 0.f, u31 = 0.f;
    float z0 = 0.f, z1 = 0.f, z2 = 0.f, z3 = 0.f;
#pragma unroll 4
    for (int e = start + half; e < end; e += 2) {
        int sj = csr2[e].x;
        float4 p = p4[e];
        unsigned fv = fin[(size_t)sj * 32 + cl];
        float f0 = b2f_lo(fv), f1 = b2f_hi(fv);
        u00 += p.x * f0; u01 += p.x * f1;
        u10 += p.y * f0; u11 += p.y * f1;
        u20 += p.z * f0; u21 += p.z * f1;
        u30 += p.w * f0; u31 += p.w * f1;
        z0 += p.x; z1 += p.y; z2 += p.z; z3 += p.w;
    }
    u00 += __shfl_xor(u00, 32, 64); u01 += __shfl_xor(u01, 32, 64);
    u10 += __shfl_xor(u10, 32, 64); u11 += __shfl_xor(u11, 32, 64);
    u20 += __shfl_xor(u20, 32, 64); u21 += __shfl_xor(u21, 32, 64);
    u30 += __shfl_xor(u30, 32, 64); u31 += __shfl_xor(u31, 32, 64);
    z0 += __shfl_xor(z0, 32, 64); z1 += __shfl_xor(z1, 32, 64);
    z2 += __shfl_xor(z2, 32, 64); z3 += __shfl_xor(z3, 32, 64);
    if (half == 0) {
        float i0 = 0.25f / z0, i1 = 0.25f / z1, i2 = 0.25f / z2,
              i3 = 0.25f / z3;
        size_t base = (size_t)node * 128;
        aggB[base + cl] = packb(u00 * i0, u01 * i0);
        aggB[base + 32 + cl] = packb(u10 * i1, u11 * i1);
        aggB[base + 64 + cl] = packb(u20 * i2, u21 * i2);
        aggB[base + 96 + cl] = packb(u30 * i3, u31 * i3);
    }
}

// ---------------- edge classifier (MFMA, 64-edge tile) ----------------------
__global__ __launch_bounds__(256) void edge_mlp3(
    const int* __restrict__ ei, const unsigned* __restrict__ UV,
    const short* __restrict__ WbT, const float* __restrict__ bb,
    const float* __restrict__ Wc, const float* __restrict__ bc,
    float* __restrict__ out, int E) {
    __shared__ __align__(16) short t1b[64 * 72];
    __shared__ __align__(16) short wbs[64 * 72];
    const int tid = threadIdx.x;
    const int eBase = blockIdx.x * 64;
    for (int idx = tid; idx < 512; idx += 256) {
        int row = idx >> 3, c = idx & 7;
        *(uint4*)(wbs + row * 72 + c * 8) =
            *(const uint4*)(WbT + row * 64 + c * 8);
    }
    {
        const int j = tid & 31;
        const int eg = tid >> 5;
        int rr[8], cc[8];
#pragma unroll
        for (int it = 0; it < 8; ++it) {
            int e = eBase + it * 8 + eg;
            rr[it] = (e < E) ? ei[e] : 0;
            cc[it] = (e < E) ? ei[E + e] : 0;
        }
#pragma unroll
        for (int it = 0; it < 8; ++it) {
            unsigned uu = UV[(size_t)rr[it] * 64 + j];
            unsigned vv = UV[(size_t)cc[it] * 64 + 32 + j];
            float lo = fmaxf(b2f_lo(uu) + b2f_lo(vv), 0.f);
            float hi = fmaxf(b2f_hi(uu) + b2f_hi(vv), 0.f);
            *(unsigned*)(t1b + (it * 8 + eg) * 72 + j * 2) = packb(lo, hi);
        }
    }
    __syncthreads();
    const int w = tid >> 6, lane = tid & 63;
    const int t = lane & 15, quad = lane >> 4;
    f32x4 acc[4];
#pragma unroll
    for (int g = 0; g < 4; ++g) acc[g] = (f32x4){0.f, 0.f, 0.f, 0.f};
#pragma unroll
    for (int kc = 0; kc < 2; ++kc) {
        bf16x8 a = *(const bf16x8*)(t1b + (w * 16 + t) * 72 + kc * 32 + quad * 8);
#pragma unroll
        for (int g = 0; g < 4; ++g) {
            bf16x8 b = *(const bf16x8*)(wbs + (g * 16 + t) * 72 + kc * 32 + quad * 8);
            acc[g] = __builtin_amdgcn_mfma_f32_16x16x32_bf16(a, b, acc[g], 0, 0, 0);
        }
    }
    float wcv[4], bbv[4];
#pragma unroll
    for (int g = 0; g < 4; ++g) {
        wcv[g] = Wc[g * 16 + t];
        bbv[g] = bb[g * 16 + t];
    }
    const float bcv = bc[0];
#pragma unroll
    for (int r = 0; r < 4; ++r) {
        int el = w * 16 + quad * 4 + r;
        float part = 0.f;
#pragma unroll
        for (int g = 0; g < 4; ++g) {
            float t1v = b2f_s(t1b[el * 72 + g * 16 + t]);
            float t2 = fmaxf(acc[g][r] + bbv[g] + t1v, 0.f);
            part += t2 * wcv[g];
        }
        part += __shfl_xor(part, 1, 64);
        part += __shfl_xor(part, 2, 64);
        part += __shfl_xor(part, 4, 64);
        part += __shfl_xor(part, 8, 64);
        int e = eBase + el;
        if (t == 0 && e < E) out[e] = part + bcv;
    }
}

extern "C" void kernel_launch(void* const* d_in, const int* in_sizes, int n_in,
                              void* d_out, int out_size, void* d_ws,
                              size_t ws_size, hipStream_t stream) {
    const float* x = (const float*)d_in[0];
    const int* ei = (const int*)d_in[1];
    const float* W0 = (const float*)d_in[2];
    const float* W1 = (const float*)d_in[3];
    const float* W2 = (const float*)d_in[4];
    const float* W3 = (const float*)d_in[5];
    const float* a_src = (const float*)d_in[6];
    const float* a_dst = (const float*)d_in[7];
    const float* gat_b = (const float*)d_in[8];
    const float* res_W = (const float*)d_in[9];
    const float* res_b = (const float*)d_in[10];
    const float* lin_W0 = (const float*)d_in[11];
    const float* lin_b0 = (const float*)d_in[12];
    const float* lin_W1 = (const float*)d_in[13];
    const float* lin_b1 = (const float*)d_in[14];
    const float* lin_W2 = (const float*)d_in[15];
    const float* lin_b2 = (const float*)d_in[16];
    float* out = (float*)d_out;

    const int N = in_sizes[0] / 128;  // 20000
    const int E = in_sizes[1] / 2;    // 320000
    const int Etot = E + N;

    char* ws = (char*)d_ws;
    unsigned* aggB = (unsigned*)ws;                    // N*256 u32 (layer0 max)
    float* featA = (float*)(aggB + (size_t)N * 256);   // N*64
    float* featB = featA + (size_t)N * 64;             // N*64
    short* featbA = (short*)(featB + (size_t)N * 64);  // N*64
    short* featbB = featbA + (size_t)N * 64;           // N*64
    float* res = (float*)(featbB + (size_t)N * 64);    // N*64
    short* xb = (short*)(res + (size_t)N * 64);        // N*128 bf16
    float* Ssrc = (float*)(xb + (size_t)N * 128);      // N*4
    float* Sdst = Ssrc + (size_t)N * 4;                // N*4
    short* WtC0 = (short*)(Sdst + (size_t)N * 4);      // 64*512
    short* WtC1 = WtC0 + 64 * 512;                     // 64*256
    short* WtC2 = WtC1 + 64 * 256;
    short* WtC3 = WtC2 + 64 * 256;
    short* WtR = WtC3 + 64 * 256;                      // 64*128
    short* WtU = WtR + 64 * 128;                       // 64*64
    short* WtV = WtU + 64 * 64;                        // 64*64
    short* WbT = WtV + 64 * 64;                        // 64*64
    float* wsd0 = (float*)(WbT + 64 * 64);             // 128*8
    float* wsdL = wsd0 + 128 * 8;                      // 3*64*8
    float* bias128 = wsdL + 3 * 64 * 8;                // 128
    int* deg = (int*)(bias128 + 128);                  // N
    int* rowstart = deg + N;                           // N+1
    int* cursor = rowstart + N + 1;                    // N
    int* locals = cursor + N;                          // N
    int* bsum = locals + N;                            // 256
    int* boff = bsum + 256;                            // 256
    int2* csr2 = (int2*)(((size_t)(boff + 256) + 15) & ~(size_t)15);  // Etot
    float4* p4 = (float4*)(((size_t)(csr2 + Etot) + 15) & ~(size_t)15);
    unsigned* UVb = aggB;  // alias: aggB dead after layer loop (N*64 u32)

    const int gemmBlocks = (N + 63) / 64;
    const int edgeBlocks = (Etot + 255) / 256;
    const int nodeW = (N + 3) / 4;
    const int scanBlocks = (N + 1023) / 1024;

    // CSR build
    hipMemsetAsync(deg, 0, (size_t)N * sizeof(int), stream);
    hist_deg<<<edgeBlocks, 256, 0, stream>>>(ei, deg, E, N);
    scan_blk<<<scanBlocks, 256, 0, stream>>>(deg, locals, bsum, N);
    scan_top<<<1, 256, 0, stream>>>(bsum, boff, scanBlocks);
    scan_add<<<(N + 256) / 256, 256, 0, stream>>>(locals, boff, rowstart,
                                                  cursor, N, Etot);
    fill_csr<<<edgeBlocks, 256, 0, stream>>>(ei, cursor, csr2, E, N);

    // weight prep + x conversion (+layer-0 scores)
    prep_weights<<<dim3(9, 16), 256, 0, stream>>>(
        W0, W1, W2, W3, res_W, lin_W0, lin_W1, lin_b0, WtC0, WtC1, WtC2, WtC3,
        WtR, WtU, WtV, WbT, bias128);
    prep_wsd<<<4, 256, 0, stream>>>(W0, W1, W2, W3, a_src, a_dst, wsd0, wsdL);
    convert_x_scores<<<nodeW, 256, 0, stream>>>(x, wsd0, (unsigned*)xb, Ssrc,
                                                Sdst, N);
    // residual projection
    mfma_gemm<128, 4, 0><<<gemmBlocks, 256, 0, stream>>>(xb, WtR, res_b, res,
                                                         nullptr, N);

    // layer 0
    edge_scores<<<edgeBlocks, 256, 0, stream>>>(csr2, Ssrc, Sdst, p4, Etot);
    gat_gather128<<<nodeW, 256, 0, stream>>>(csr2, rowstart, p4,
                                             (const unsigned*)xb, aggB, N);
    gemm_layer<512, true><<<gemmBlocks, 256, 0, stream>>>(
        (const short*)aggB, WtC0, gat_b, res, wsdL, featA, featbA, Ssrc, Sdst,
        N);
    // layers 1-3
    const short* WtCs[3] = {WtC1, WtC2, WtC3};
    float* feats[4] = {featA, featB, featA, featB};
    short* featbs[4] = {featbA, featbB, featbA, featbB};
    for (int i = 1; i < 4; ++i) {
        edge_scores<<<edgeBlocks, 256, 0, stream>>>(csr2, Ssrc, Sdst, p4, Etot);
        gat_gather64<<<nodeW, 256, 0, stream>>>(
            csr2, rowstart, p4, (const unsigned*)featbs[i - 1], aggB, N);
        if (i < 3)
            gemm_layer<256, true><<<gemmBlocks, 256, 0, stream>>>(
                (const short*)aggB, WtCs[i - 1], gat_b + i * 64, feats[i - 1],
                wsdL + i * 64 * 8, feats[i], featbs[i], Ssrc, Sdst, N);
        else
            gemm_layer<256, false><<<gemmBlocks, 256, 0, stream>>>(
                (const short*)aggB, WtCs[i - 1], gat_b + i * 64, feats[i - 1],
                nullptr, feats[i], featbs[i], Ssrc, Sdst, N);
    }

    // edge classifier heads: UV = feat3@[W0_top|W0_bot] + [b0|0]
    mfma_gemm<64, 8, 2><<<gemmBlocks, 256, 0, stream>>>(
        featbB, WtU, bias128, nullptr, (short*)UVb, N);
    edge_mlp3<<<(E + 63) / 64, 256, 0, stream>>>(ei, UVb, WbT, lin_b1, lin_W2,
                                                 lin_b2, out, E);
}